// Round 3
// 404.093 us; speedup vs baseline: 1.0146x; 1.0146x over previous
//
#include <hip/hip_runtime.h>

// Problem constants (from reference): N=50000 nodes, K=16 neighbors,
// CT=CS=64 channels, S=4 mixture size, OUT=64 outputs.
#define CT 64
#define CS 64
#define K_NB 16
#define S_SZ 4
#define OUT_C 64

// Native clang vector type: __builtin_nontemporal_store rejects the
// HIP_vector_type<float,4> wrapper class but accepts this.
typedef float vfloat4 __attribute__((ext_vector_type(4)));

// ---------------------------------------------------------------------------
// k0: per-row assignment logits.
//   t[r][s]  = x[r]   @ Wt + bt   (r over N)
//   sl[r][s] = src[r] @ Ws + bs
// One thread per row; Wt/Ws rows are float4 broadcasts (cached).
// ---------------------------------------------------------------------------
__global__ __launch_bounds__(256) void k0_logits(
    const float* __restrict__ x, const float* __restrict__ src,
    const float* __restrict__ Wt, const float* __restrict__ bt,
    const float* __restrict__ Ws, const float* __restrict__ bs,
    float* __restrict__ t_out, float* __restrict__ sl_out, int N)
{
    int r = blockIdx.x * blockDim.x + threadIdx.x;
    if (r >= N) return;
    const float4* xv  = (const float4*)(x   + (size_t)r * CT);
    const float4* sv  = (const float4*)(src + (size_t)r * CS);
    const float4* Wt4 = (const float4*)Wt;   // [64] rows of float4 (S=4)
    const float4* Ws4 = (const float4*)Ws;
    float4 at = *(const float4*)bt;
    float4 as = *(const float4*)bs;
    #pragma unroll
    for (int c4 = 0; c4 < 16; ++c4) {
        float4 xq = xv[c4];
        float4 sq = sv[c4];
        float xs_[4] = {xq.x, xq.y, xq.z, xq.w};
        float ss_[4] = {sq.x, sq.y, sq.z, sq.w};
        #pragma unroll
        for (int u = 0; u < 4; ++u) {
            float4 wt = Wt4[c4 * 4 + u];
            float4 ws = Ws4[c4 * 4 + u];
            at.x = fmaf(xs_[u], wt.x, at.x);
            at.y = fmaf(xs_[u], wt.y, at.y);
            at.z = fmaf(xs_[u], wt.z, at.z);
            at.w = fmaf(xs_[u], wt.w, at.w);
            as.x = fmaf(ss_[u], ws.x, as.x);
            as.y = fmaf(ss_[u], ws.y, as.y);
            as.z = fmaf(ss_[u], ws.z, as.z);
            as.w = fmaf(ss_[u], ws.w, as.w);
        }
    }
    ((float4*)t_out)[r]  = at;
    ((float4*)sl_out)[r] = as;
}

// ---------------------------------------------------------------------------
// k1: per-node transformed messages (the 16x dedup win).
//   Z[j][s][o] = sum_c src[j][c] * W_lin[s][c][o] + b_lin[s][o]
// Thread = column col = s*64+o. Each thread holds its W_lin column slice
// (64 values over c) in registers; src row is broadcast from LDS
// (ds_read_b128, same-address broadcast = conflict-free).
// Z stores stay CACHEABLE on purpose: k2 gathers them and wants L3 hits.
// ---------------------------------------------------------------------------
__global__ __launch_bounds__(256, 4) void k1_z(
    const float* __restrict__ src, const float* __restrict__ W_lin,
    const float* __restrict__ b_lin, float* __restrict__ Z, int N)
{
    const int col = threadIdx.x;          // col = s*64 + o
    const int s = col >> 6, o = col & 63;
    float w[64];
    #pragma unroll
    for (int c = 0; c < 64; ++c)
        w[c] = W_lin[s * 4096 + (c << 6) + o];   // [s][c][o], coalesced in o
    const float bl = b_lin[col];                 // [s][o] flat == col
    __shared__ float lsrc[64];
    for (int j = blockIdx.x; j < N; j += gridDim.x) {
        if (threadIdx.x < 16)
            ((float4*)lsrc)[threadIdx.x] =
                ((const float4*)(src + ((size_t)j << 6)))[threadIdx.x];
        __syncthreads();
        const float4* l4 = (const float4*)lsrc;
        float a0 = bl, a1 = 0.f, a2 = 0.f, a3 = 0.f;  // 4-way ILP chains
        #pragma unroll
        for (int c4 = 0; c4 < 16; ++c4) {
            float4 s4 = l4[c4];
            a0 = fmaf(s4.x, w[c4 * 4 + 0], a0);
            a1 = fmaf(s4.y, w[c4 * 4 + 1], a1);
            a2 = fmaf(s4.z, w[c4 * 4 + 2], a2);
            a3 = fmaf(s4.w, w[c4 * 4 + 3], a3);
        }
        Z[(size_t)j * 256 + col] = (a0 + a1) + (a2 + a3);
        __syncthreads();
    }
}

// ---------------------------------------------------------------------------
// k2: gather + softmax(S=4) + assignment-weighted mean.
//   out[p][o] = sum_s softmax_s(sl[j]+t[n])[s] * Z[j][s][o] / 4,  j=idx[p]
// Block = one node n (256 threads = 16 p-values x 16 o-quads).
// KEY CHANGE vs round 0: `out` is written with NON-TEMPORAL stores.
// The 204.8 MB write stream was 4x the 51.2 MB Z working set and evicted
// Z from L3 continuously -> FETCH_SIZE was 424 MB (7x over ideal ~60 MB).
// nt stores keep the write stream from allocating in L2/L3 so the random
// Z gather stays L3-resident. nidx is read-once -> nt load too.
// Z/t/sl loads stay cacheable (that's the reuse we're protecting).
// ---------------------------------------------------------------------------
__global__ __launch_bounds__(256) void k2_out(
    const int* __restrict__ nidx, const float* __restrict__ t_in,
    const float* __restrict__ sl_in, const float* __restrict__ Z,
    float* __restrict__ out)
{
    const int T = blockIdx.x * 256 + threadIdx.x;
    const int p = T >> 4;          // (n,k) flat pair
    const int quad = T & 15;       // o-quad: o = quad*4 .. quad*4+3
    const int n = p >> 4;          // K = 16
    const int j = __builtin_nontemporal_load(nidx + p);
    float4 tv = ((const float4*)t_in)[n];    // block-uniform, cached
    float4 sv = ((const float4*)sl_in)[j];   // small table, cached
    float l0 = tv.x + sv.x, l1 = tv.y + sv.y;
    float l2 = tv.z + sv.z, l3 = tv.w + sv.w;
    float m = fmaxf(fmaxf(l0, l1), fmaxf(l2, l3));
    float e0 = __expf(l0 - m), e1 = __expf(l1 - m);
    float e2 = __expf(l2 - m), e3 = __expf(l3 - m);
    float inv = 0.25f / (e0 + e1 + e2 + e3);   // softmax norm * (1/size)
    const float4* zb = (const float4*)Z + (size_t)j * 64 + quad;
    float4 z0 = zb[0], z1 = zb[16], z2 = zb[32], z3 = zb[48];
    vfloat4 o;
    o.x = (e0 * z0.x + e1 * z1.x + e2 * z2.x + e3 * z3.x) * inv;
    o.y = (e0 * z0.y + e1 * z1.y + e2 * z2.y + e3 * z3.y) * inv;
    o.z = (e0 * z0.z + e1 * z1.z + e2 * z2.z + e3 * z3.z) * inv;
    o.w = (e0 * z0.w + e1 * z1.w + e2 * z2.w + e3 * z3.w) * inv;
    __builtin_nontemporal_store(o, (vfloat4*)out + (size_t)p * 16 + quad);
}

extern "C" void kernel_launch(void* const* d_in, const int* in_sizes, int n_in,
                              void* d_out, int out_size, void* d_ws, size_t ws_size,
                              hipStream_t stream)
{
    const float* x   = (const float*)d_in[0];
    const float* src = (const float*)d_in[1];
    const int*   idx = (const int*)d_in[2];
    const float* Wt  = (const float*)d_in[3];
    const float* bt  = (const float*)d_in[4];
    const float* Ws  = (const float*)d_in[5];
    const float* bs  = (const float*)d_in[6];
    const float* Wl  = (const float*)d_in[7];
    const float* bl  = (const float*)d_in[8];
    float* out = (float*)d_out;

    const int N = in_sizes[0] / CT;   // 50000

    // Workspace layout (floats): Z[N*256] | t[N*4] | sl[N*4]  = 52.8 MB
    float* Z  = (float*)d_ws;
    float* t  = Z + (size_t)N * 256;
    float* sl = t + (size_t)N * 4;

    hipLaunchKernelGGL(k0_logits, dim3((N + 255) / 256), dim3(256), 0, stream,
                       x, src, Wt, bt, Ws, bs, t, sl, N);
    hipLaunchKernelGGL(k1_z, dim3(1024), dim3(256), 0, stream,
                       src, Wl, bl, Z, N);
    // N*K*16 threads total = N blocks of 256 (K=16, OUT=64)
    hipLaunchKernelGGL(k2_out, dim3(N), dim3(256), 0, stream,
                       idx, t, sl, Z, out);
}